// Round 1
// baseline (2620.975 us; speedup 1.0000x reference)
//
#include <hip/hip_runtime.h>

typedef unsigned short u16;
typedef __bf16 bf16x8 __attribute__((ext_vector_type(8)));
typedef float floatx4 __attribute__((ext_vector_type(4)));

__device__ inline u16 f2bf(float f) {
    unsigned int u = __float_as_uint(f);
    unsigned int r = (u + 0x7FFFu + ((u >> 16) & 1u)) >> 16;
    return (u16)r;
}
__device__ inline float bf2f(u16 h) {
    return __uint_as_float(((unsigned int)h) << 16);
}

// ---------------------------------------------------------------------------
// Layer 0: direct conv 3->64, 32x32, input NCHW fp32, output NHWC bf16
// block = 256 threads = 4 pixels x 64 co
// ---------------------------------------------------------------------------
__global__ __launch_bounds__(256) void conv0_kernel(
    const float* __restrict__ x, const float* __restrict__ w,
    const float* __restrict__ bias, u16* __restrict__ out)
{
    __shared__ float ws[27 * 64];
    for (int i = threadIdx.x; i < 27 * 64; i += 256) {
        int co = i & 63;
        int k  = i >> 6;          // k = ci*9 + s
        ws[i]  = w[(co * 3 + (k / 9)) * 9 + (k % 9)];
    }
    __syncthreads();
    int t = threadIdx.x;
    int co = t & 63;
    int pixel = blockIdx.x * 4 + (t >> 6);       // [0, 512*1024)
    int b  = pixel >> 10;
    int rm = pixel & 1023;
    int y  = rm >> 5;
    int xx = rm & 31;
    float acc = bias[co];
    #pragma unroll
    for (int ci = 0; ci < 3; ci++) {
        #pragma unroll
        for (int r = 0; r < 3; r++) {
            int yy = y + r - 1;
            #pragma unroll
            for (int c3 = 0; c3 < 3; c3++) {
                int x2 = xx + c3 - 1;
                float v = 0.f;
                if ((unsigned)yy < 32u && (unsigned)x2 < 32u)
                    v = x[((b * 3 + ci) * 32 + yy) * 32 + x2];
                acc += v * ws[(ci * 9 + r * 3 + c3) * 64 + co];
            }
        }
    }
    out[(size_t)pixel * 64 + co] = f2bf(fmaxf(acc, 0.f));
}

// ---------------------------------------------------------------------------
// Weight repack: [Cout][Cin][3][3] fp32 -> [Cout][9][Cin] bf16
// ---------------------------------------------------------------------------
__global__ void repack_w(const float* __restrict__ w, u16* __restrict__ wt,
                         int Cin, int total)
{
    int i = blockIdx.x * 256 + threadIdx.x;
    if (i >= total) return;
    int ci = i % Cin;
    int rest = i / Cin;
    int s = rest % 9;
    int co = rest / 9;
    wt[i] = f2bf(w[(co * Cin + ci) * 9 + s]);
}

// ---------------------------------------------------------------------------
// Conv as shift-GEMM, bf16 MFMA 16x16x32.
// in:  NHWC [512,H,H,Cin] bf16, wt: [Cout][9][Cin] bf16, out: NHWC bf16
// M = 512*H*H (spatial-major rows), N = Cout, K = 9*Cin.
// BM=128, BK=64, BN template (64 or 128). 256 threads = 4 waves (2x2).
// ---------------------------------------------------------------------------
template <int BN>
__global__ __launch_bounds__(256) void conv_gemm(
    const u16* __restrict__ in, const u16* __restrict__ wt,
    const float* __restrict__ bias, u16* __restrict__ out,
    int H, int Cin, int Cout, int logHW, int logW)
{
    constexpr int BM = 128, BK = 64, BKP = BK + 8;  // +8 u16 = +16B row pad
    constexpr int NT = BN / 32;                      // n-tiles per wave
    __shared__ u16 As[BM * BKP];
    __shared__ u16 Bs[BN * BKP];

    const int Nblocks = Cout / BN;
    const int m0 = (blockIdx.x / Nblocks) * BM;
    const int n0 = (blockIdx.x % Nblocks) * BN;

    const int t    = threadIdx.x;
    const int lane = t & 63;
    const int wave = t >> 6;
    const int quad = lane >> 4;
    const int l16  = lane & 15;
    const int wm   = wave >> 1;   // 0..1  (64 rows each)
    const int wn   = wave & 1;    // 0..1  (BN/2 cols each)

    const int W  = H;
    const int HW = 1 << logHW;

    floatx4 acc[4][NT];
    #pragma unroll
    for (int i = 0; i < 4; i++)
        #pragma unroll
        for (int j = 0; j < NT; j++)
            acc[i][j] = (floatx4){0.f, 0.f, 0.f, 0.f};

    for (int s = 0; s < 9; s++) {
        const int dy = s / 3 - 1;
        const int dx = s % 3 - 1;
        for (int kb = 0; kb < Cin; kb += BK) {
            // ---- stage A tile: BM x BK, predicated im2col gather ----
            for (int c = t; c < BM * BK / 8; c += 256) {
                int row  = c >> 3;
                int col8 = c & 7;
                int m  = m0 + row;
                int b  = m >> logHW;
                int rm = m & (HW - 1);
                int y  = rm >> logW;
                int xx = rm & (W - 1);
                int ys = y + dy, xs = xx + dx;
                uint4 val = make_uint4(0u, 0u, 0u, 0u);
                if ((unsigned)ys < (unsigned)H && (unsigned)xs < (unsigned)W) {
                    const uint4* p = (const uint4*)(in +
                        ((size_t)((b * H + ys) * W + xs) * Cin + kb + col8 * 8));
                    val = *p;
                }
                *(uint4*)(As + row * BKP + col8 * 8) = val;
            }
            // ---- stage B^T tile: BN x BK (k contiguous per row) ----
            for (int c = t; c < BN * BK / 8; c += 256) {
                int n    = c >> 3;
                int col8 = c & 7;
                const uint4* p = (const uint4*)(wt +
                    ((size_t)(n0 + n) * 9 + s) * Cin + kb + col8 * 8);
                *(uint4*)(Bs + n * BKP + col8 * 8) = *p;
            }
            __syncthreads();
            // ---- MFMA over this K-block ----
            #pragma unroll
            for (int kk = 0; kk < BK; kk += 32) {
                bf16x8 af[4], bfr[NT];
                #pragma unroll
                for (int mt = 0; mt < 4; mt++)
                    af[mt] = *(const bf16x8*)(As +
                        (wm * 64 + mt * 16 + l16) * BKP + kk + quad * 8);
                #pragma unroll
                for (int nt = 0; nt < NT; nt++)
                    bfr[nt] = *(const bf16x8*)(Bs +
                        (wn * (BN / 2) + nt * 16 + l16) * BKP + kk + quad * 8);
                #pragma unroll
                for (int mt = 0; mt < 4; mt++)
                    #pragma unroll
                    for (int nt = 0; nt < NT; nt++)
                        acc[mt][nt] = __builtin_amdgcn_mfma_f32_16x16x32_bf16(
                            af[mt], bfr[nt], acc[mt][nt], 0, 0, 0);
            }
            __syncthreads();
        }
    }
    // ---- epilogue: bias + relu + bf16 store, NHWC ----
    #pragma unroll
    for (int mt = 0; mt < 4; mt++) {
        #pragma unroll
        for (int nt = 0; nt < NT; nt++) {
            #pragma unroll
            for (int r = 0; r < 4; r++) {
                int mg = m0 + wm * 64 + mt * 16 + quad * 4 + r;
                int ng = n0 + wn * (BN / 2) + nt * 16 + l16;
                float v = acc[mt][nt][r] + bias[ng];
                v = fmaxf(v, 0.f);
                out[(size_t)mg * Cout + ng] = f2bf(v);
            }
        }
    }
}

// ---------------------------------------------------------------------------
// 2x2 maxpool, NHWC bf16
// ---------------------------------------------------------------------------
__global__ void pool2(const u16* __restrict__ in, u16* __restrict__ out,
                      int Hout, int C, int total)
{
    int i = blockIdx.x * 256 + threadIdx.x;
    if (i >= total) return;
    int c = i % C;
    int rest = i / C;
    int x = rest % Hout; rest /= Hout;
    int y = rest % Hout;
    int b = rest / Hout;
    int Hin = Hout * 2;
    const u16* p = in + ((size_t)((b * Hin + 2 * y) * Hin + 2 * x) * C + c);
    float v0 = bf2f(p[0]);
    float v1 = bf2f(p[C]);
    float v2 = bf2f(p[(size_t)Hin * C]);
    float v3 = bf2f(p[(size_t)Hin * C + C]);
    out[i] = f2bf(fmaxf(fmaxf(v0, v1), fmaxf(v2, v3)));
}

// ---------------------------------------------------------------------------
// bf16 -> fp32 convert
// ---------------------------------------------------------------------------
__global__ void bf2f_kernel(const u16* __restrict__ in, float* __restrict__ out, int n)
{
    int i = blockIdx.x * 256 + threadIdx.x;
    if (i < n) out[i] = bf2f(in[i]);
}

// ---------------------------------------------------------------------------
// small dense: out[b][j] = in[b][:] @ w[:, j] + bias[j]  (w is [K][N] fp32)
// ---------------------------------------------------------------------------
__global__ void lin_kernel(const float* __restrict__ in, const float* __restrict__ w,
                           const float* __restrict__ bias, float* __restrict__ out,
                           int K, int N, int total, int relu)
{
    int i = blockIdx.x * 256 + threadIdx.x;
    if (i >= total) return;
    int b = i / N, j = i % N;
    float acc = bias[j];
    for (int k = 0; k < K; k++)
        acc += in[b * K + k] * w[k * N + j];
    if (relu) acc = fmaxf(acc, 0.f);
    out[i] = acc;
}

// ---------------------------------------------------------------------------
// graph_pre = sigmoid(low @ low^T), graph_gt = (target_i == target_j)
// ---------------------------------------------------------------------------
__global__ void graph_kernel(const float* __restrict__ low, float* __restrict__ gpre,
                             const int* __restrict__ target, float* __restrict__ ggt)
{
    int i = blockIdx.x * 256 + threadIdx.x;   // 512*512
    int r = i >> 9, c = i & 511;
    float acc = 0.f;
    #pragma unroll 8
    for (int k = 0; k < 128; k++)
        acc += low[r * 128 + k] * low[c * 128 + k];
    gpre[i] = 1.f / (1.f + __expf(-acc));
    ggt[i] = (target[r] == target[c]) ? 1.f : 0.f;
}

// ---------------------------------------------------------------------------
extern "C" void kernel_launch(void* const* d_in, const int* in_sizes, int n_in,
                              void* d_out, int out_size, void* d_ws, size_t ws_size,
                              hipStream_t stream)
{
    const float* x      = (const float*)d_in[0];
    const int*   target = (const int*)d_in[1];
    const float* conv_w[13];
    const float* conv_b[13];
    for (int i = 0; i < 13; i++) {
        conv_w[i] = (const float*)d_in[2 + 2 * i];
        conv_b[i] = (const float*)d_in[3 + 2 * i];
    }
    const float* lin1_w = (const float*)d_in[28];
    const float* lin1_b = (const float*)d_in[29];
    const float* lin2_w = (const float*)d_in[30];
    const float* lin2_b = (const float*)d_in[31];
    const float* cls_w  = (const float*)d_in[32];
    const float* cls_b  = (const float*)d_in[33];
    float* out = (float*)d_out;

    static const int cin_arr[13]  = {3, 64, 64, 128, 128, 256, 256, 256, 512, 512, 512, 512, 512};
    static const int cout_arr[13] = {64, 64, 128, 128, 256, 256, 256, 512, 512, 512, 512, 512, 512};

    char* ws = (char*)d_ws;
    size_t off = 0;
    u16* R0 = (u16*)(ws + off); off += (size_t)512 * 32 * 32 * 64 * 2;
    u16* R1 = (u16*)(ws + off); off += (size_t)512 * 32 * 32 * 64 * 2;
    u16* wt[13];
    for (int i = 1; i < 13; i++) {
        wt[i] = (u16*)(ws + off);
        off += (size_t)cout_arr[i] * 9 * cin_arr[i] * 2;
    }
    float* featf  = (float*)(ws + off); off += (size_t)512 * 512 * 4;
    float* hbuf   = (float*)(ws + off); off += (size_t)512 * 256 * 4;
    float* lowbuf = (float*)(ws + off); off += (size_t)512 * 128 * 4;

    // repack conv weights (layers 1..12) to [Cout][9][Cin] bf16
    for (int i = 1; i < 13; i++) {
        int total = cout_arr[i] * 9 * cin_arr[i];
        repack_w<<<(total + 255) / 256, 256, 0, stream>>>(conv_w[i], wt[i], cin_arr[i], total);
    }

    // layer 0
    conv0_kernel<<<512 * 1024 / 4, 256, 0, stream>>>(x, conv_w[0], conv_b[0], R0);

    auto launch_conv = [&](int li, int Hl, u16* inb, u16* outb) {
        int Cin = cin_arr[li], Cout = cout_arr[li];
        int M = 512 * Hl * Hl;
        int logW = __builtin_ctz(Hl);
        int logHW = 2 * logW;
        if (Cout >= 128) {
            conv_gemm<128><<<(M / 128) * (Cout / 128), 256, 0, stream>>>(
                inb, wt[li], conv_b[li], outb, Hl, Cin, Cout, logHW, logW);
        } else {
            conv_gemm<64><<<(M / 128) * (Cout / 64), 256, 0, stream>>>(
                inb, wt[li], conv_b[li], outb, Hl, Cin, Cout, logHW, logW);
        }
    };
    auto launch_pool = [&](int Hout, int C, u16* inb, u16* outb) {
        int total = 512 * Hout * Hout * C;
        pool2<<<(total + 255) / 256, 256, 0, stream>>>(inb, outb, Hout, C, total);
    };

    launch_conv(1, 32, R0, R1);
    launch_pool(16, 64, R1, R0);
    launch_conv(2, 16, R0, R1);
    launch_conv(3, 16, R1, R0);
    launch_pool(8, 128, R0, R1);
    launch_conv(4, 8, R1, R0);
    launch_conv(5, 8, R0, R1);
    launch_conv(6, 8, R1, R0);
    launch_pool(4, 256, R0, R1);
    launch_conv(7, 4, R1, R0);
    launch_conv(8, 4, R0, R1);
    launch_conv(9, 4, R1, R0);
    launch_pool(2, 512, R0, R1);
    launch_conv(10, 2, R1, R0);
    launch_conv(11, 2, R0, R1);
    launch_conv(12, 2, R1, R0);
    launch_pool(1, 512, R0, R1);   // feat (bf16) now in R1: [512,512]

    bf2f_kernel<<<(512 * 512 + 255) / 256, 256, 0, stream>>>(R1, featf, 512 * 512);

    // h = relu(feat @ lin1_w + lin1_b)   [512,256]
    lin_kernel<<<(512 * 256 + 255) / 256, 256, 0, stream>>>(
        featf, lin1_w, lin1_b, hbuf, 512, 256, 512 * 256, 1);
    // low = h @ lin2_w + lin2_b          [512,128]
    lin_kernel<<<(512 * 128 + 255) / 256, 256, 0, stream>>>(
        hbuf, lin2_w, lin2_b, lowbuf, 256, 128, 512 * 128, 0);
    // graph_pre, graph_gt                [512,512] each
    graph_kernel<<<512 * 512 / 256, 256, 0, stream>>>(
        lowbuf, out + 5120, target, out + 5120 + 262144);
    // out = feat @ cls_w + cls_b  (mat == Identity due to source bug)
    lin_kernel<<<(512 * 10 + 255) / 256, 256, 0, stream>>>(
        featf, cls_w, cls_b, out, 512, 10, 512 * 10, 0);
}

// Round 2
// 1929.303 us; speedup vs baseline: 1.3585x; 1.3585x over previous
//
#include <hip/hip_runtime.h>

typedef unsigned short u16;
typedef __bf16 bf16x8 __attribute__((ext_vector_type(8)));
typedef float floatx4 __attribute__((ext_vector_type(4)));

__device__ inline u16 f2bf(float f) {
    unsigned int u = __float_as_uint(f);
    unsigned int r = (u + 0x7FFFu + ((u >> 16) & 1u)) >> 16;
    return (u16)r;
}
__device__ inline float bf2f(u16 h) {
    return __uint_as_float(((unsigned int)h) << 16);
}

// ---------------------------------------------------------------------------
// Layer 0: direct conv 3->64, 32x32. Block = 4 waves; each wave = one image
// row x 64 co. Input slab (6 rows x 36 padded cols x 3 ch) staged in LDS,
// weights held in 27 VGPRs per lane, 4 pixels per inner step.
// ---------------------------------------------------------------------------
__global__ __launch_bounds__(256) void conv0_kernel(
    const float* __restrict__ x, const float* __restrict__ w,
    const float* __restrict__ bias, u16* __restrict__ out)
{
    __shared__ __align__(16) float xs[3][6][36];
    const int t  = threadIdx.x;
    const int b  = blockIdx.x >> 3;           // image
    const int y0 = (blockIdx.x & 7) * 4;      // first of 4 output rows

    // stage rows y0-1 .. y0+4, padded cols (-1..34) -> [6][36], zero borders
    for (int i = t; i < 3 * 6 * 36; i += 256) {
        int ci  = i / 216;
        int rem = i % 216;
        int r   = rem / 36;
        int c   = rem % 36;
        int gy  = y0 - 1 + r;
        int gx  = c - 1;
        float v = 0.f;
        if ((unsigned)gy < 32u && (unsigned)gx < 32u)
            v = x[((b * 3 + ci) * 32 + gy) * 32 + gx];
        xs[ci][r][c] = v;
    }
    const int lane = t & 63;
    const int wv   = t >> 6;
    float wr[27];
    #pragma unroll
    for (int k = 0; k < 27; k++) wr[k] = w[lane * 27 + k];
    const float bz = bias[lane];
    __syncthreads();

    const int y = y0 + wv;
    u16* orow = out + ((size_t)(b * 1024 + y * 32) * 64) + lane;
    for (int xg = 0; xg < 32; xg += 4) {
        float a0 = bz, a1 = bz, a2 = bz, a3 = bz;
        #pragma unroll
        for (int ci = 0; ci < 3; ci++) {
            #pragma unroll
            for (int rr = 0; rr < 3; rr++) {
                const float* row = &xs[ci][wv + rr][0];
                float4 c03 = *(const float4*)(row + xg);
                float2 c45 = *(const float2*)(row + xg + 4);
                float w0 = wr[ci * 9 + rr * 3 + 0];
                float w1 = wr[ci * 9 + rr * 3 + 1];
                float w2 = wr[ci * 9 + rr * 3 + 2];
                a0 += c03.x * w0 + c03.y * w1 + c03.z * w2;
                a1 += c03.y * w0 + c03.z * w1 + c03.w * w2;
                a2 += c03.z * w0 + c03.w * w1 + c45.x * w2;
                a3 += c03.w * w0 + c45.x * w1 + c45.y * w2;
            }
        }
        orow[(xg + 0) * 64] = f2bf(fmaxf(a0, 0.f));
        orow[(xg + 1) * 64] = f2bf(fmaxf(a1, 0.f));
        orow[(xg + 2) * 64] = f2bf(fmaxf(a2, 0.f));
        orow[(xg + 3) * 64] = f2bf(fmaxf(a3, 0.f));
    }
}

// ---------------------------------------------------------------------------
// Weight repack: [Cout][Cin][3][3] fp32 -> [Cout][9][Cin] bf16
// ---------------------------------------------------------------------------
__global__ void repack_w(const float* __restrict__ w, u16* __restrict__ wt,
                         int Cin, int total)
{
    int i = blockIdx.x * 256 + threadIdx.x;
    if (i >= total) return;
    int ci = i % Cin;
    int rest = i / Cin;
    int s = rest % 9;
    int co = rest / 9;
    wt[i] = f2bf(w[(co * Cin + ci) * 9 + s]);
}

// ---------------------------------------------------------------------------
// Conv as shift-GEMM, bf16 MFMA 16x16x32, register-prefetch pipeline.
// in: NHWC bf16, wt: [Cout][9][Cin] bf16, out: NHWC bf16.
// BM=128, BK=64, XOR-swizzled LDS (no pad), flattened (s,kb) loop with
// hoisted im2col base addresses; next tile's global loads issued before the
// current tile's MFMAs so load latency overlaps compute.
// ---------------------------------------------------------------------------
template <int BN>
__global__ __launch_bounds__(256) void conv_gemm(
    const u16* __restrict__ in, const u16* __restrict__ wt,
    const float* __restrict__ bias, u16* __restrict__ out,
    int H, int Cin, int Cout, int logHW, int logW)
{
    constexpr int BM = 128, BK = 64;
    constexpr int NT   = BN / 32;        // n-tiles per wave
    constexpr int NB_A = 4;              // BM*8 chunks / 256 threads
    constexpr int NB_B = BN * 8 / 256;   // 4 (BN=128) or 2 (BN=64)
    __shared__ u16 As[BM * BK];
    __shared__ u16 Bs[BN * BK];

    const int Nblocks = Cout / BN;
    const int m0 = (blockIdx.x / Nblocks) * BM;
    const int n0 = (blockIdx.x % Nblocks) * BN;

    const int t    = threadIdx.x;
    const int lane = t & 63;
    const int wave = t >> 6;
    const int quad = lane >> 4;
    const int l16  = lane & 15;
    const int wm   = wave >> 1;
    const int wn   = wave & 1;
    const int W    = H;
    const int HW   = 1 << logHW;
    const int col8 = t & 7;
    const int r0   = t >> 3;

    // hoisted A-row decomposition (invariant across the K loop)
    int ab_y[NB_A], ab_x[NB_A], ab_p[NB_A];
    #pragma unroll
    for (int j = 0; j < NB_A; j++) {
        int m  = m0 + r0 + 32 * j;
        int b  = m >> logHW;
        int rm = m & (HW - 1);
        int y  = rm >> logW;
        int xx = rm & (W - 1);
        ab_y[j] = y;
        ab_x[j] = xx;
        ab_p[j] = ((b * H + y) * W + xx) * Cin + col8 * 8;
    }
    int bb_p[NB_B];
    #pragma unroll
    for (int j = 0; j < NB_B; j++)
        bb_p[j] = (n0 + r0 + 32 * j) * 9 * Cin + col8 * 8;

    const int KB = Cin >> 6;
    const int T  = 9 * KB;

    uint4 ar[NB_A], br[NB_B];

    auto prefetch = [&](int s, int kb) {
        int dy  = s / 3 - 1;
        int dx  = s % 3 - 1;
        int off = (dy * W + dx) * Cin + kb;
        #pragma unroll
        for (int j = 0; j < NB_A; j++) {
            bool v = ((unsigned)(ab_y[j] + dy) < (unsigned)H) &&
                     ((unsigned)(ab_x[j] + dx) < (unsigned)W);
            uint4 val = make_uint4(0u, 0u, 0u, 0u);
            if (v) val = *(const uint4*)(in + ab_p[j] + off);
            ar[j] = val;
        }
        int offb = s * Cin + kb;   // == it*BK
        #pragma unroll
        for (int j = 0; j < NB_B; j++)
            br[j] = *(const uint4*)(wt + bb_p[j] + offb);
    };
    auto store_tiles = [&]() {
        #pragma unroll
        for (int j = 0; j < NB_A; j++) {
            int row = r0 + 32 * j;
            *(uint4*)(As + row * 64 + ((col8 ^ (row & 7)) * 8)) = ar[j];
        }
        #pragma unroll
        for (int j = 0; j < NB_B; j++) {
            int row = r0 + 32 * j;
            *(uint4*)(Bs + row * 64 + ((col8 ^ (row & 7)) * 8)) = br[j];
        }
    };

    floatx4 acc[4][NT];
    #pragma unroll
    for (int i = 0; i < 4; i++)
        #pragma unroll
        for (int j = 0; j < NT; j++)
            acc[i][j] = (floatx4){0.f, 0.f, 0.f, 0.f};

    prefetch(0, 0);
    int s_cur = 0, kb_cur = 0;
    for (int it = 0; it < T; it++) {
        store_tiles();
        __syncthreads();
        int kb_n = kb_cur + BK, s_n = s_cur;
        if (kb_n == Cin) { kb_n = 0; s_n++; }
        if (it + 1 < T) prefetch(s_n, kb_n);   // loads fly over the MFMAs
        kb_cur = kb_n; s_cur = s_n;
        #pragma unroll
        for (int kk = 0; kk < BK; kk += 32) {
            bf16x8 af[4], bfv[NT];
            #pragma unroll
            for (int mt = 0; mt < 4; mt++) {
                int row = wm * 64 + mt * 16 + l16;
                int cb  = (kk >> 3) + quad;
                af[mt] = *(const bf16x8*)(As + row * 64 + ((cb ^ (row & 7)) * 8));
            }
            #pragma unroll
            for (int nt = 0; nt < NT; nt++) {
                int row = wn * (BN / 2) + nt * 16 + l16;
                int cb  = (kk >> 3) + quad;
                bfv[nt] = *(const bf16x8*)(Bs + row * 64 + ((cb ^ (row & 7)) * 8));
            }
            #pragma unroll
            for (int mt = 0; mt < 4; mt++)
                #pragma unroll
                for (int nt = 0; nt < NT; nt++)
                    acc[mt][nt] = __builtin_amdgcn_mfma_f32_16x16x32_bf16(
                        af[mt], bfv[nt], acc[mt][nt], 0, 0, 0);
        }
        __syncthreads();
    }

    // epilogue: bias + relu + bf16 store, NHWC
    #pragma unroll
    for (int mt = 0; mt < 4; mt++) {
        #pragma unroll
        for (int nt = 0; nt < NT; nt++) {
            #pragma unroll
            for (int r = 0; r < 4; r++) {
                int mg = m0 + wm * 64 + mt * 16 + quad * 4 + r;
                int ng = n0 + wn * (BN / 2) + nt * 16 + l16;
                float v = acc[mt][nt][r] + bias[ng];
                v = fmaxf(v, 0.f);
                out[(size_t)mg * Cout + ng] = f2bf(v);
            }
        }
    }
}

// ---------------------------------------------------------------------------
// 2x2 maxpool, NHWC bf16
// ---------------------------------------------------------------------------
__global__ void pool2(const u16* __restrict__ in, u16* __restrict__ out,
                      int Hout, int C, int total)
{
    int i = blockIdx.x * 256 + threadIdx.x;
    if (i >= total) return;
    int c = i % C;
    int rest = i / C;
    int x = rest % Hout; rest /= Hout;
    int y = rest % Hout;
    int b = rest / Hout;
    int Hin = Hout * 2;
    const u16* p = in + ((size_t)((b * Hin + 2 * y) * Hin + 2 * x) * C + c);
    float v0 = bf2f(p[0]);
    float v1 = bf2f(p[C]);
    float v2 = bf2f(p[(size_t)Hin * C]);
    float v3 = bf2f(p[(size_t)Hin * C + C]);
    out[i] = f2bf(fmaxf(fmaxf(v0, v1), fmaxf(v2, v3)));
}

// ---------------------------------------------------------------------------
__global__ void bf2f_kernel(const u16* __restrict__ in, float* __restrict__ out, int n)
{
    int i = blockIdx.x * 256 + threadIdx.x;
    if (i < n) out[i] = bf2f(in[i]);
}

// ---------------------------------------------------------------------------
// small dense: out[b][j] = in[b][:] @ w[:, j] + bias[j]  (w is [K][N] fp32)
// ---------------------------------------------------------------------------
__global__ void lin_kernel(const float* __restrict__ in, const float* __restrict__ w,
                           const float* __restrict__ bias, float* __restrict__ out,
                           int K, int N, int total, int relu)
{
    int i = blockIdx.x * 256 + threadIdx.x;
    if (i >= total) return;
    int b = i / N, j = i % N;
    float acc = bias[j];
    for (int k = 0; k < K; k++)
        acc += in[b * K + k] * w[k * N + j];
    if (relu) acc = fmaxf(acc, 0.f);
    out[i] = acc;
}

// ---------------------------------------------------------------------------
// graph_pre = sigmoid(low @ low^T), graph_gt = (target_i == target_j)
// ---------------------------------------------------------------------------
__global__ void graph_kernel(const float* __restrict__ low, float* __restrict__ gpre,
                             const int* __restrict__ target, float* __restrict__ ggt)
{
    int i = blockIdx.x * 256 + threadIdx.x;   // 512*512
    int r = i >> 9, c = i & 511;
    float acc = 0.f;
    #pragma unroll 8
    for (int k = 0; k < 128; k++)
        acc += low[r * 128 + k] * low[c * 128 + k];
    gpre[i] = 1.f / (1.f + __expf(-acc));
    ggt[i] = (target[r] == target[c]) ? 1.f : 0.f;
}

// ---------------------------------------------------------------------------
extern "C" void kernel_launch(void* const* d_in, const int* in_sizes, int n_in,
                              void* d_out, int out_size, void* d_ws, size_t ws_size,
                              hipStream_t stream)
{
    const float* x      = (const float*)d_in[0];
    const int*   target = (const int*)d_in[1];
    const float* conv_w[13];
    const float* conv_b[13];
    for (int i = 0; i < 13; i++) {
        conv_w[i] = (const float*)d_in[2 + 2 * i];
        conv_b[i] = (const float*)d_in[3 + 2 * i];
    }
    const float* lin1_w = (const float*)d_in[28];
    const float* lin1_b = (const float*)d_in[29];
    const float* lin2_w = (const float*)d_in[30];
    const float* lin2_b = (const float*)d_in[31];
    const float* cls_w  = (const float*)d_in[32];
    const float* cls_b  = (const float*)d_in[33];
    float* out = (float*)d_out;

    static const int cin_arr[13]  = {3, 64, 64, 128, 128, 256, 256, 256, 512, 512, 512, 512, 512};
    static const int cout_arr[13] = {64, 64, 128, 128, 256, 256, 256, 512, 512, 512, 512, 512, 512};

    char* ws = (char*)d_ws;
    size_t off = 0;
    u16* R0 = (u16*)(ws + off); off += (size_t)512 * 32 * 32 * 64 * 2;
    u16* R1 = (u16*)(ws + off); off += (size_t)512 * 32 * 32 * 64 * 2;
    u16* wt[13];
    for (int i = 1; i < 13; i++) {
        wt[i] = (u16*)(ws + off);
        off += (size_t)cout_arr[i] * 9 * cin_arr[i] * 2;
    }
    float* featf  = (float*)(ws + off); off += (size_t)512 * 512 * 4;
    float* hbuf   = (float*)(ws + off); off += (size_t)512 * 256 * 4;
    float* lowbuf = (float*)(ws + off); off += (size_t)512 * 128 * 4;

    for (int i = 1; i < 13; i++) {
        int total = cout_arr[i] * 9 * cin_arr[i];
        repack_w<<<(total + 255) / 256, 256, 0, stream>>>(conv_w[i], wt[i], cin_arr[i], total);
    }

    // layer 0: 512 images x 8 row-groups
    conv0_kernel<<<512 * 8, 256, 0, stream>>>(x, conv_w[0], conv_b[0], R0);

    auto launch_conv = [&](int li, int Hl, u16* inb, u16* outb) {
        int Cin = cin_arr[li], Cout = cout_arr[li];
        int M = 512 * Hl * Hl;
        int logW = __builtin_ctz(Hl);
        int logHW = 2 * logW;
        if (Cout >= 128) {
            conv_gemm<128><<<(M / 128) * (Cout / 128), 256, 0, stream>>>(
                inb, wt[li], conv_b[li], outb, Hl, Cin, Cout, logHW, logW);
        } else {
            conv_gemm<64><<<(M / 128) * (Cout / 64), 256, 0, stream>>>(
                inb, wt[li], conv_b[li], outb, Hl, Cin, Cout, logHW, logW);
        }
    };
    auto launch_pool = [&](int Hout, int C, u16* inb, u16* outb) {
        int total = 512 * Hout * Hout * C;
        pool2<<<(total + 255) / 256, 256, 0, stream>>>(inb, outb, Hout, C, total);
    };

    launch_conv(1, 32, R0, R1);
    launch_pool(16, 64, R1, R0);
    launch_conv(2, 16, R0, R1);
    launch_conv(3, 16, R1, R0);
    launch_pool(8, 128, R0, R1);
    launch_conv(4, 8, R1, R0);
    launch_conv(5, 8, R0, R1);
    launch_conv(6, 8, R1, R0);
    launch_pool(4, 256, R0, R1);
    launch_conv(7, 4, R1, R0);
    launch_conv(8, 4, R0, R1);
    launch_conv(9, 4, R1, R0);
    launch_pool(2, 512, R0, R1);
    launch_conv(10, 2, R1, R0);
    launch_conv(11, 2, R0, R1);
    launch_conv(12, 2, R1, R0);
    launch_pool(1, 512, R0, R1);   // feat bf16 [512,512] in R1

    bf2f_kernel<<<(512 * 512 + 255) / 256, 256, 0, stream>>>(R1, featf, 512 * 512);

    lin_kernel<<<(512 * 256 + 255) / 256, 256, 0, stream>>>(
        featf, lin1_w, lin1_b, hbuf, 512, 256, 512 * 256, 1);
    lin_kernel<<<(512 * 128 + 255) / 256, 256, 0, stream>>>(
        hbuf, lin2_w, lin2_b, lowbuf, 256, 128, 512 * 128, 0);
    graph_kernel<<<512 * 512 / 256, 256, 0, stream>>>(
        lowbuf, out + 5120, target, out + 5120 + 262144);
    lin_kernel<<<(512 * 10 + 255) / 256, 256, 0, stream>>>(
        featf, cls_w, cls_b, out, 512, 10, 512 * 10, 0);
}

// Round 3
// 1578.194 us; speedup vs baseline: 1.6607x; 1.2225x over previous
//
#include <hip/hip_runtime.h>

typedef unsigned short u16;
typedef __bf16 bf16x8 __attribute__((ext_vector_type(8)));
typedef float floatx4 __attribute__((ext_vector_type(4)));

__device__ inline u16 f2bf(float f) {
    unsigned int u = __float_as_uint(f);
    unsigned int r = (u + 0x7FFFu + ((u >> 16) & 1u)) >> 16;
    return (u16)r;
}
__device__ inline float bf2f(u16 h) {
    return __uint_as_float(((unsigned int)h) << 16);
}

// ---------------------------------------------------------------------------
// Layer 0: direct conv 3->64, 32x32. Block = 4 waves; each wave = one image
// row x 64 co. Input slab staged in LDS, weights in 27 VGPRs per lane.
// ---------------------------------------------------------------------------
__global__ __launch_bounds__(256) void conv0_kernel(
    const float* __restrict__ x, const float* __restrict__ w,
    const float* __restrict__ bias, u16* __restrict__ out)
{
    __shared__ __align__(16) float xs[3][6][36];
    const int t  = threadIdx.x;
    const int b  = blockIdx.x >> 3;
    const int y0 = (blockIdx.x & 7) * 4;

    for (int i = t; i < 3 * 6 * 36; i += 256) {
        int ci  = i / 216;
        int rem = i % 216;
        int r   = rem / 36;
        int c   = rem % 36;
        int gy  = y0 - 1 + r;
        int gx  = c - 1;
        float v = 0.f;
        if ((unsigned)gy < 32u && (unsigned)gx < 32u)
            v = x[((b * 3 + ci) * 32 + gy) * 32 + gx];
        xs[ci][r][c] = v;
    }
    const int lane = t & 63;
    const int wv   = t >> 6;
    float wr[27];
    #pragma unroll
    for (int k = 0; k < 27; k++) wr[k] = w[lane * 27 + k];
    const float bz = bias[lane];
    __syncthreads();

    const int y = y0 + wv;
    u16* orow = out + ((size_t)(b * 1024 + y * 32) * 64) + lane;
    for (int xg = 0; xg < 32; xg += 4) {
        float a0 = bz, a1 = bz, a2 = bz, a3 = bz;
        #pragma unroll
        for (int ci = 0; ci < 3; ci++) {
            #pragma unroll
            for (int rr = 0; rr < 3; rr++) {
                const float* row = &xs[ci][wv + rr][0];
                float4 c03 = *(const float4*)(row + xg);
                float2 c45 = *(const float2*)(row + xg + 4);
                float w0 = wr[ci * 9 + rr * 3 + 0];
                float w1 = wr[ci * 9 + rr * 3 + 1];
                float w2 = wr[ci * 9 + rr * 3 + 2];
                a0 += c03.x * w0 + c03.y * w1 + c03.z * w2;
                a1 += c03.y * w0 + c03.z * w1 + c03.w * w2;
                a2 += c03.z * w0 + c03.w * w1 + c45.x * w2;
                a3 += c03.w * w0 + c45.x * w1 + c45.y * w2;
            }
        }
        orow[(xg + 0) * 64] = f2bf(fmaxf(a0, 0.f));
        orow[(xg + 1) * 64] = f2bf(fmaxf(a1, 0.f));
        orow[(xg + 2) * 64] = f2bf(fmaxf(a2, 0.f));
        orow[(xg + 3) * 64] = f2bf(fmaxf(a3, 0.f));
    }
}

// ---------------------------------------------------------------------------
// Weight repack: [Cout][Cin][3][3] fp32 -> [Cout][9][Cin] bf16
// ---------------------------------------------------------------------------
__global__ void repack_w(const float* __restrict__ w, u16* __restrict__ wt,
                         int Cin, int total)
{
    int i = blockIdx.x * 256 + threadIdx.x;
    if (i >= total) return;
    int ci = i % Cin;
    int rest = i / Cin;
    int s = rest % 9;
    int co = rest / 9;
    wt[i] = f2bf(w[(co * Cin + ci) * 9 + s]);
}

// transpose+cvt: w[K][N] fp32 -> wt[N][K] bf16
__global__ void repack_lin(const float* __restrict__ w, u16* __restrict__ wt,
                           int K, int N, int total)
{
    int i = blockIdx.x * 256 + threadIdx.x;
    if (i >= total) return;
    int n = i % N, k = i / N;
    wt[(size_t)n * K + k] = f2bf(w[(size_t)k * N + n]);
}

// ---------------------------------------------------------------------------
// Conv as shift-GEMM, bf16 MFMA 16x16x32, register-prefetch pipeline.
// ---------------------------------------------------------------------------
template <int BN>
__global__ __launch_bounds__(256) void conv_gemm(
    const u16* __restrict__ in, const u16* __restrict__ wt,
    const float* __restrict__ bias, u16* __restrict__ out,
    int H, int Cin, int Cout, int logHW, int logW)
{
    constexpr int BM = 128, BK = 64;
    constexpr int NT   = BN / 32;
    constexpr int NB_A = 4;
    constexpr int NB_B = BN * 8 / 256;
    __shared__ u16 As[BM * BK];
    __shared__ u16 Bs[BN * BK];

    const int Nblocks = Cout / BN;
    const int m0 = (blockIdx.x / Nblocks) * BM;
    const int n0 = (blockIdx.x % Nblocks) * BN;

    const int t    = threadIdx.x;
    const int lane = t & 63;
    const int wave = t >> 6;
    const int quad = lane >> 4;
    const int l16  = lane & 15;
    const int wm   = wave >> 1;
    const int wn   = wave & 1;
    const int W    = H;
    const int HW   = 1 << logHW;
    const int col8 = t & 7;
    const int r0   = t >> 3;

    int ab_y[NB_A], ab_x[NB_A], ab_p[NB_A];
    #pragma unroll
    for (int j = 0; j < NB_A; j++) {
        int m  = m0 + r0 + 32 * j;
        int b  = m >> logHW;
        int rm = m & (HW - 1);
        int y  = rm >> logW;
        int xx = rm & (W - 1);
        ab_y[j] = y;
        ab_x[j] = xx;
        ab_p[j] = ((b * H + y) * W + xx) * Cin + col8 * 8;
    }
    int bb_p[NB_B];
    #pragma unroll
    for (int j = 0; j < NB_B; j++)
        bb_p[j] = (n0 + r0 + 32 * j) * 9 * Cin + col8 * 8;

    const int KB = Cin >> 6;
    const int T  = 9 * KB;

    uint4 ar[NB_A], br[NB_B];

    auto prefetch = [&](int s, int kb) {
        int dy  = s / 3 - 1;
        int dx  = s % 3 - 1;
        int off = (dy * W + dx) * Cin + kb;
        #pragma unroll
        for (int j = 0; j < NB_A; j++) {
            bool v = ((unsigned)(ab_y[j] + dy) < (unsigned)H) &&
                     ((unsigned)(ab_x[j] + dx) < (unsigned)W);
            uint4 val = make_uint4(0u, 0u, 0u, 0u);
            if (v) val = *(const uint4*)(in + ab_p[j] + off);
            ar[j] = val;
        }
        int offb = s * Cin + kb;
        #pragma unroll
        for (int j = 0; j < NB_B; j++)
            br[j] = *(const uint4*)(wt + bb_p[j] + offb);
    };
    auto store_tiles = [&]() {
        #pragma unroll
        for (int j = 0; j < NB_A; j++) {
            int row = r0 + 32 * j;
            *(uint4*)(As + row * 64 + ((col8 ^ (row & 7)) * 8)) = ar[j];
        }
        #pragma unroll
        for (int j = 0; j < NB_B; j++) {
            int row = r0 + 32 * j;
            *(uint4*)(Bs + row * 64 + ((col8 ^ (row & 7)) * 8)) = br[j];
        }
    };

    floatx4 acc[4][NT];
    #pragma unroll
    for (int i = 0; i < 4; i++)
        #pragma unroll
        for (int j = 0; j < NT; j++)
            acc[i][j] = (floatx4){0.f, 0.f, 0.f, 0.f};

    prefetch(0, 0);
    int s_cur = 0, kb_cur = 0;
    for (int it = 0; it < T; it++) {
        store_tiles();
        __syncthreads();
        int kb_n = kb_cur + BK, s_n = s_cur;
        if (kb_n == Cin) { kb_n = 0; s_n++; }
        if (it + 1 < T) prefetch(s_n, kb_n);
        kb_cur = kb_n; s_cur = s_n;
        #pragma unroll
        for (int kk = 0; kk < BK; kk += 32) {
            bf16x8 af[4], bfv[NT];
            #pragma unroll
            for (int mt = 0; mt < 4; mt++) {
                int row = wm * 64 + mt * 16 + l16;
                int cb  = (kk >> 3) + quad;
                af[mt] = *(const bf16x8*)(As + row * 64 + ((cb ^ (row & 7)) * 8));
            }
            #pragma unroll
            for (int nt = 0; nt < NT; nt++) {
                int row = wn * (BN / 2) + nt * 16 + l16;
                int cb  = (kk >> 3) + quad;
                bfv[nt] = *(const bf16x8*)(Bs + row * 64 + ((cb ^ (row & 7)) * 8));
            }
            #pragma unroll
            for (int mt = 0; mt < 4; mt++)
                #pragma unroll
                for (int nt = 0; nt < NT; nt++)
                    acc[mt][nt] = __builtin_amdgcn_mfma_f32_16x16x32_bf16(
                        af[mt], bfv[nt], acc[mt][nt], 0, 0, 0);
        }
        __syncthreads();
    }

    #pragma unroll
    for (int mt = 0; mt < 4; mt++) {
        #pragma unroll
        for (int nt = 0; nt < NT; nt++) {
            #pragma unroll
            for (int r = 0; r < 4; r++) {
                int mg = m0 + wm * 64 + mt * 16 + quad * 4 + r;
                int ng = n0 + wn * (BN / 2) + nt * 16 + l16;
                float v = acc[mt][nt][r] + bias[ng];
                v = fmaxf(v, 0.f);
                out[(size_t)mg * Cout + ng] = f2bf(v);
            }
        }
    }
}

// ---------------------------------------------------------------------------
// Generic small GEMM: out[M,N] = act(A[M,K](bf16) @ Bt[N,K](bf16)^T + bias)
// 64x64 tile per block, 4 waves, MFMA 16x16x32.
// ---------------------------------------------------------------------------
template <bool RELU, bool OUTBF>
__global__ __launch_bounds__(256) void gemm64(
    const u16* __restrict__ A, const u16* __restrict__ Bt,
    const float* __restrict__ bias, void* __restrict__ outv,
    int M, int N, int K)
{
    constexpr int LDP = 72;           // 64 + 8 u16 pad
    __shared__ u16 As[64 * LDP];
    __shared__ u16 Bs[64 * LDP];

    const int nb = N >> 6;
    const int m0 = (blockIdx.x / nb) * 64;
    const int n0 = (blockIdx.x % nb) * 64;
    const int t = threadIdx.x, lane = t & 63, wave = t >> 6;
    const int quad = lane >> 4, l16 = lane & 15;
    const int wm = wave >> 1, wn = wave & 1;
    const int col8 = t & 7, r0 = t >> 3;

    floatx4 acc[2][2];
    #pragma unroll
    for (int i = 0; i < 2; i++)
        #pragma unroll
        for (int j = 0; j < 2; j++)
            acc[i][j] = (floatx4){0.f, 0.f, 0.f, 0.f};

    for (int kb = 0; kb < K; kb += 64) {
        #pragma unroll
        for (int j = 0; j < 2; j++) {
            int row = r0 + 32 * j;
            *(uint4*)(As + row * LDP + col8 * 8) =
                *(const uint4*)(A + (size_t)(m0 + row) * K + kb + col8 * 8);
            *(uint4*)(Bs + row * LDP + col8 * 8) =
                *(const uint4*)(Bt + (size_t)(n0 + row) * K + kb + col8 * 8);
        }
        __syncthreads();
        #pragma unroll
        for (int kk = 0; kk < 64; kk += 32) {
            bf16x8 af[2], bfv[2];
            #pragma unroll
            for (int mt = 0; mt < 2; mt++)
                af[mt] = *(const bf16x8*)(As + (wm * 32 + mt * 16 + l16) * LDP + kk + quad * 8);
            #pragma unroll
            for (int nt = 0; nt < 2; nt++)
                bfv[nt] = *(const bf16x8*)(Bs + (wn * 32 + nt * 16 + l16) * LDP + kk + quad * 8);
            #pragma unroll
            for (int mt = 0; mt < 2; mt++)
                #pragma unroll
                for (int nt = 0; nt < 2; nt++)
                    acc[mt][nt] = __builtin_amdgcn_mfma_f32_16x16x32_bf16(
                        af[mt], bfv[nt], acc[mt][nt], 0, 0, 0);
        }
        __syncthreads();
    }
    #pragma unroll
    for (int mt = 0; mt < 2; mt++) {
        #pragma unroll
        for (int nt = 0; nt < 2; nt++) {
            #pragma unroll
            for (int r = 0; r < 4; r++) {
                int mg = m0 + wm * 32 + mt * 16 + quad * 4 + r;
                int ng = n0 + wn * 32 + nt * 16 + l16;
                float v = acc[mt][nt][r] + bias[ng];
                if (RELU) v = fmaxf(v, 0.f);
                if (OUTBF) ((u16*)outv)[(size_t)mg * N + ng] = f2bf(v);
                else       ((float*)outv)[(size_t)mg * N + ng] = v;
            }
        }
    }
}

// ---------------------------------------------------------------------------
// graph: 64x64 tile of sigmoid(low @ low^T) + graph_gt, fp32, LDS tiled.
// ---------------------------------------------------------------------------
__global__ __launch_bounds__(256) void graph_tile(
    const float* __restrict__ low, const int* __restrict__ target,
    float* __restrict__ gpre, float* __restrict__ ggt)
{
    __shared__ float Al[64 * 132];   // [row][k], pad->2-way max
    __shared__ float Bl[128 * 68];   // [k][col], pad->2-way max
    const int t = threadIdx.x;
    const int gr0 = (blockIdx.x >> 3) * 64;
    const int gc0 = (blockIdx.x & 7) * 64;

    #pragma unroll
    for (int j = 0; j < 32; j++) {
        int flat = t + 256 * j;      // 8192 elements
        int k = flat & 127;
        int rc = flat >> 7;
        Al[rc * 132 + k] = low[(size_t)(gr0 + rc) * 128 + k];
        Bl[k * 68 + rc]  = low[(size_t)(gc0 + rc) * 128 + k];
    }
    __syncthreads();

    const int tx = t & 15, ty = t >> 4;
    float acc[4][4];
    #pragma unroll
    for (int r = 0; r < 4; r++)
        #pragma unroll
        for (int c = 0; c < 4; c++) acc[r][c] = 0.f;

    for (int k = 0; k < 128; k++) {
        float a[4], b[4];
        #pragma unroll
        for (int r = 0; r < 4; r++) a[r] = Al[(ty * 4 + r) * 132 + k];
        #pragma unroll
        for (int c = 0; c < 4; c++) b[c] = Bl[k * 68 + tx * 4 + c];
        #pragma unroll
        for (int r = 0; r < 4; r++)
            #pragma unroll
            for (int c = 0; c < 4; c++) acc[r][c] += a[r] * b[c];
    }
    #pragma unroll
    for (int r = 0; r < 4; r++) {
        int row = gr0 + ty * 4 + r;
        int tr  = target[row];
        float4 gp, gg;
        float* pp = (float*)&gp;
        float* gg_ = (float*)&gg;
        #pragma unroll
        for (int c = 0; c < 4; c++) {
            pp[c]  = 1.f / (1.f + __expf(-acc[r][c]));
            gg_[c] = (tr == target[gc0 + tx * 4 + c]) ? 1.f : 0.f;
        }
        *(float4*)(gpre + (size_t)row * 512 + gc0 + tx * 4) = gp;
        *(float4*)(ggt  + (size_t)row * 512 + gc0 + tx * 4) = gg;
    }
}

// ---------------------------------------------------------------------------
// cls: out[512,10] = feat(bf16) @ cls_w + cls_b. One wave per row.
// ---------------------------------------------------------------------------
__global__ __launch_bounds__(256) void cls_kernel(
    const u16* __restrict__ feat, const float* __restrict__ w,
    const float* __restrict__ bias, float* __restrict__ out)
{
    __shared__ float ws[5120];
    const int t = threadIdx.x;
    for (int i = t; i < 5120; i += 256) ws[i] = w[i];
    __syncthreads();
    const int lane = t & 63;
    const int row  = blockIdx.x * 4 + (t >> 6);
    float a[10];
    #pragma unroll
    for (int j = 0; j < 10; j++) a[j] = 0.f;
    #pragma unroll
    for (int i = 0; i < 8; i++) {
        int k = i * 64 + lane;
        float f = bf2f(feat[(size_t)row * 512 + k]);
        #pragma unroll
        for (int j = 0; j < 10; j++) a[j] += f * ws[k * 10 + j];
    }
    #pragma unroll
    for (int j = 0; j < 10; j++)
        #pragma unroll
        for (int off = 32; off > 0; off >>= 1)
            a[j] += __shfl_down(a[j], off, 64);
    if (lane == 0) {
        #pragma unroll
        for (int j = 0; j < 10; j++) out[row * 10 + j] = a[j] + bias[j];
    }
}

// ---------------------------------------------------------------------------
// 2x2 maxpool, NHWC bf16
// ---------------------------------------------------------------------------
__global__ void pool2(const u16* __restrict__ in, u16* __restrict__ out,
                      int Hout, int C, int total)
{
    int i = blockIdx.x * 256 + threadIdx.x;
    if (i >= total) return;
    int c = i % C;
    int rest = i / C;
    int x = rest % Hout; rest /= Hout;
    int y = rest % Hout;
    int b = rest / Hout;
    int Hin = Hout * 2;
    const u16* p = in + ((size_t)((b * Hin + 2 * y) * Hin + 2 * x) * C + c);
    float v0 = bf2f(p[0]);
    float v1 = bf2f(p[C]);
    float v2 = bf2f(p[(size_t)Hin * C]);
    float v3 = bf2f(p[(size_t)Hin * C + C]);
    out[i] = f2bf(fmaxf(fmaxf(v0, v1), fmaxf(v2, v3)));
}

// ---------------------------------------------------------------------------
extern "C" void kernel_launch(void* const* d_in, const int* in_sizes, int n_in,
                              void* d_out, int out_size, void* d_ws, size_t ws_size,
                              hipStream_t stream)
{
    const float* x      = (const float*)d_in[0];
    const int*   target = (const int*)d_in[1];
    const float* conv_w[13];
    const float* conv_b[13];
    for (int i = 0; i < 13; i++) {
        conv_w[i] = (const float*)d_in[2 + 2 * i];
        conv_b[i] = (const float*)d_in[3 + 2 * i];
    }
    const float* lin1_w = (const float*)d_in[28];
    const float* lin1_b = (const float*)d_in[29];
    const float* lin2_w = (const float*)d_in[30];
    const float* lin2_b = (const float*)d_in[31];
    const float* cls_w  = (const float*)d_in[32];
    const float* cls_b  = (const float*)d_in[33];
    float* out = (float*)d_out;

    static const int cin_arr[13]  = {3, 64, 64, 128, 128, 256, 256, 256, 512, 512, 512, 512, 512};
    static const int cout_arr[13] = {64, 64, 128, 128, 256, 256, 256, 512, 512, 512, 512, 512, 512};

    char* ws = (char*)d_ws;
    size_t off = 0;
    u16* R0 = (u16*)(ws + off); off += (size_t)512 * 32 * 32 * 64 * 2;
    u16* R1 = (u16*)(ws + off); off += (size_t)512 * 32 * 32 * 64 * 2;
    u16* wt[13];
    for (int i = 1; i < 13; i++) {
        wt[i] = (u16*)(ws + off);
        off += (size_t)cout_arr[i] * 9 * cin_arr[i] * 2;
    }
    u16* wtl1 = (u16*)(ws + off); off += (size_t)256 * 512 * 2;
    u16* wtl2 = (u16*)(ws + off); off += (size_t)128 * 256 * 2;
    u16* hbuf = (u16*)(ws + off); off += (size_t)512 * 256 * 2;
    float* lowbuf = (float*)(ws + off); off += (size_t)512 * 128 * 4;

    for (int i = 1; i < 13; i++) {
        int total = cout_arr[i] * 9 * cin_arr[i];
        repack_w<<<(total + 255) / 256, 256, 0, stream>>>(conv_w[i], wt[i], cin_arr[i], total);
    }
    repack_lin<<<(512 * 256) / 256, 256, 0, stream>>>(lin1_w, wtl1, 512, 256, 512 * 256);
    repack_lin<<<(256 * 128) / 256, 256, 0, stream>>>(lin2_w, wtl2, 256, 128, 256 * 128);

    conv0_kernel<<<512 * 8, 256, 0, stream>>>(x, conv_w[0], conv_b[0], R0);

    auto launch_conv = [&](int li, int Hl, u16* inb, u16* outb) {
        int Cin = cin_arr[li], Cout = cout_arr[li];
        int M = 512 * Hl * Hl;
        int logW = __builtin_ctz(Hl);
        int logHW = 2 * logW;
        if (Cout >= 128) {
            conv_gemm<128><<<(M / 128) * (Cout / 128), 256, 0, stream>>>(
                inb, wt[li], conv_b[li], outb, Hl, Cin, Cout, logHW, logW);
        } else {
            conv_gemm<64><<<(M / 128) * (Cout / 64), 256, 0, stream>>>(
                inb, wt[li], conv_b[li], outb, Hl, Cin, Cout, logHW, logW);
        }
    };
    auto launch_pool = [&](int Hout, int C, u16* inb, u16* outb) {
        int total = 512 * Hout * Hout * C;
        pool2<<<(total + 255) / 256, 256, 0, stream>>>(inb, outb, Hout, C, total);
    };

    launch_conv(1, 32, R0, R1);
    launch_pool(16, 64, R1, R0);
    launch_conv(2, 16, R0, R1);
    launch_conv(3, 16, R1, R0);
    launch_pool(8, 128, R0, R1);
    launch_conv(4, 8, R1, R0);
    launch_conv(5, 8, R0, R1);
    launch_conv(6, 8, R1, R0);
    launch_pool(4, 256, R0, R1);
    launch_conv(7, 4, R1, R0);
    launch_conv(8, 4, R0, R1);
    launch_conv(9, 4, R1, R0);
    launch_pool(2, 512, R0, R1);
    launch_conv(10, 2, R1, R0);
    launch_conv(11, 2, R0, R1);
    launch_conv(12, 2, R1, R0);
    launch_pool(1, 512, R0, R1);   // feat bf16 [512,512] in R1

    // h = relu(feat @ lin1_w + b1)  -> bf16 [512,256]
    gemm64<true, true><<<(512 / 64) * (256 / 64), 256, 0, stream>>>(
        R1, wtl1, lin1_b, hbuf, 512, 256, 512);
    // low = h @ lin2_w + b2  -> fp32 [512,128]
    gemm64<false, false><<<(512 / 64) * (128 / 64), 256, 0, stream>>>(
        hbuf, wtl2, lin2_b, lowbuf, 512, 128, 256);
    // graph_pre + graph_gt
    graph_tile<<<64, 256, 0, stream>>>(lowbuf, target, out + 5120, out + 5120 + 262144);
    // out = feat @ cls_w + cls_b
    cls_kernel<<<128, 256, 0, stream>>>(R1, cls_w, cls_b, out);
}

// Round 4
// 1133.646 us; speedup vs baseline: 2.3120x; 1.3921x over previous
//
#include <hip/hip_runtime.h>

typedef unsigned short u16;
typedef __bf16 bf16x8 __attribute__((ext_vector_type(8)));
typedef float floatx4 __attribute__((ext_vector_type(4)));

__device__ inline u16 f2bf(float f) {
    unsigned int u = __float_as_uint(f);
    unsigned int r = (u + 0x7FFFu + ((u >> 16) & 1u)) >> 16;
    return (u16)r;
}
__device__ inline float bf2f(u16 h) {
    return __uint_as_float(((unsigned int)h) << 16);
}

// ---------------------------------------------------------------------------
// Layer 0: direct conv 3->64, 32x32.
// ---------------------------------------------------------------------------
__global__ __launch_bounds__(256) void conv0_kernel(
    const float* __restrict__ x, const float* __restrict__ w,
    const float* __restrict__ bias, u16* __restrict__ out)
{
    __shared__ __align__(16) float xs[3][6][36];
    const int t  = threadIdx.x;
    const int b  = blockIdx.x >> 3;
    const int y0 = (blockIdx.x & 7) * 4;

    for (int i = t; i < 3 * 6 * 36; i += 256) {
        int ci  = i / 216;
        int rem = i % 216;
        int r   = rem / 36;
        int c   = rem % 36;
        int gy  = y0 - 1 + r;
        int gx  = c - 1;
        float v = 0.f;
        if ((unsigned)gy < 32u && (unsigned)gx < 32u)
            v = x[((b * 3 + ci) * 32 + gy) * 32 + gx];
        xs[ci][r][c] = v;
    }
    const int lane = t & 63;
    const int wv   = t >> 6;
    float wr[27];
    #pragma unroll
    for (int k = 0; k < 27; k++) wr[k] = w[lane * 27 + k];
    const float bz = bias[lane];
    __syncthreads();

    const int y = y0 + wv;
    u16* orow = out + ((size_t)(b * 1024 + y * 32) * 64) + lane;
    for (int xg = 0; xg < 32; xg += 4) {
        float a0 = bz, a1 = bz, a2 = bz, a3 = bz;
        #pragma unroll
        for (int ci = 0; ci < 3; ci++) {
            #pragma unroll
            for (int rr = 0; rr < 3; rr++) {
                const float* row = &xs[ci][wv + rr][0];
                float4 c03 = *(const float4*)(row + xg);
                float2 c45 = *(const float2*)(row + xg + 4);
                float w0 = wr[ci * 9 + rr * 3 + 0];
                float w1 = wr[ci * 9 + rr * 3 + 1];
                float w2 = wr[ci * 9 + rr * 3 + 2];
                a0 += c03.x * w0 + c03.y * w1 + c03.z * w2;
                a1 += c03.y * w0 + c03.z * w1 + c03.w * w2;
                a2 += c03.z * w0 + c03.w * w1 + c45.x * w2;
                a3 += c03.w * w0 + c45.x * w1 + c45.y * w2;
            }
        }
        orow[(xg + 0) * 64] = f2bf(fmaxf(a0, 0.f));
        orow[(xg + 1) * 64] = f2bf(fmaxf(a1, 0.f));
        orow[(xg + 2) * 64] = f2bf(fmaxf(a2, 0.f));
        orow[(xg + 3) * 64] = f2bf(fmaxf(a3, 0.f));
    }
}

// ---------------------------------------------------------------------------
__global__ void repack_w(const float* __restrict__ w, u16* __restrict__ wt,
                         int Cin, int total)
{
    int i = blockIdx.x * 256 + threadIdx.x;
    if (i >= total) return;
    int ci = i % Cin;
    int rest = i / Cin;
    int s = rest % 9;
    int co = rest / 9;
    wt[i] = f2bf(w[(co * Cin + ci) * 9 + s]);
}

__global__ void repack_lin(const float* __restrict__ w, u16* __restrict__ wt,
                           int K, int N, int total)
{
    int i = blockIdx.x * 256 + threadIdx.x;
    if (i >= total) return;
    int n = i % N, k = i / N;
    wt[(size_t)n * K + k] = f2bf(w[(size_t)k * N + n]);
}

// ---------------------------------------------------------------------------
// Conv shift-GEMM, bf16 MFMA 16x16x32, register prefetch + double-buffered
// LDS (one barrier per K-iter) + optional split-K (fp32 partials).
// ---------------------------------------------------------------------------
template <int BN>
__global__ __launch_bounds__(256) void conv_gemm(
    const u16* __restrict__ in, const u16* __restrict__ wt,
    const float* __restrict__ bias, u16* __restrict__ out,
    float* __restrict__ partial, size_t pstride,
    int H, int Cin, int Cout, int logHW, int logW, int splitN)
{
    constexpr int BM = 128, BK = 64;
    constexpr int NT   = BN / 32;
    constexpr int NB_A = 4;
    constexpr int NB_B = BN * 8 / 256;
    __shared__ u16 As[2][BM * BK];
    __shared__ u16 Bs[2][BN * BK];

    const int Nblocks = Cout / BN;
    const int bid  = blockIdx.x;
    const int sp   = bid % splitN;
    const int tile = bid / splitN;
    const int m0 = (tile / Nblocks) * BM;
    const int n0 = (tile % Nblocks) * BN;

    const int t    = threadIdx.x;
    const int lane = t & 63;
    const int wave = t >> 6;
    const int quad = lane >> 4;
    const int l16  = lane & 15;
    const int wm   = wave >> 1;
    const int wn   = wave & 1;
    const int W    = H;
    const int HW   = 1 << logHW;
    const int col8 = t & 7;
    const int r0   = t >> 3;

    int ab_y[NB_A], ab_x[NB_A], ab_p[NB_A];
    #pragma unroll
    for (int j = 0; j < NB_A; j++) {
        int m  = m0 + r0 + 32 * j;
        int b  = m >> logHW;
        int rm = m & (HW - 1);
        int y  = rm >> logW;
        int xx = rm & (W - 1);
        ab_y[j] = y;
        ab_x[j] = xx;
        ab_p[j] = ((b * H + y) * W + xx) * Cin + col8 * 8;
    }
    int bb_p[NB_B];
    #pragma unroll
    for (int j = 0; j < NB_B; j++)
        bb_p[j] = (n0 + r0 + 32 * j) * 9 * Cin + col8 * 8;

    const int KB  = Cin >> 6;
    const int T   = 9 * KB;
    const int len = T / splitN;
    const int it0 = sp * len;
    int s_cur  = it0 / KB;
    int kb_cur = (it0 % KB) * BK;

    uint4 ar[NB_A], br[NB_B];

    auto prefetch = [&](int s, int kb) {
        int dy  = s / 3 - 1;
        int dx  = s % 3 - 1;
        int off = (dy * W + dx) * Cin + kb;
        #pragma unroll
        for (int j = 0; j < NB_A; j++) {
            bool v = ((unsigned)(ab_y[j] + dy) < (unsigned)H) &&
                     ((unsigned)(ab_x[j] + dx) < (unsigned)W);
            uint4 val = make_uint4(0u, 0u, 0u, 0u);
            if (v) val = *(const uint4*)(in + ab_p[j] + off);
            ar[j] = val;
        }
        int offb = s * Cin + kb;
        #pragma unroll
        for (int j = 0; j < NB_B; j++)
            br[j] = *(const uint4*)(wt + bb_p[j] + offb);
    };
    auto advance = [&]() {
        kb_cur += BK;
        if (kb_cur == Cin) { kb_cur = 0; s_cur++; }
    };
    auto store_tiles = [&](int bsel) {
        #pragma unroll
        for (int j = 0; j < NB_A; j++) {
            int row = r0 + 32 * j;
            *(uint4*)(As[bsel] + row * 64 + ((col8 ^ (row & 7)) * 8)) = ar[j];
        }
        #pragma unroll
        for (int j = 0; j < NB_B; j++) {
            int row = r0 + 32 * j;
            *(uint4*)(Bs[bsel] + row * 64 + ((col8 ^ (row & 7)) * 8)) = br[j];
        }
    };

    floatx4 acc[4][NT];
    #pragma unroll
    for (int i = 0; i < 4; i++)
        #pragma unroll
        for (int j = 0; j < NT; j++)
            acc[i][j] = (floatx4){0.f, 0.f, 0.f, 0.f};

    prefetch(s_cur, kb_cur);
    advance();
    store_tiles(0);
    int cur = 0;
    for (int it = 0; it < len; it++) {
        __syncthreads();
        if (it + 1 < len) { prefetch(s_cur, kb_cur); advance(); }
        #pragma unroll
        for (int kk = 0; kk < BK; kk += 32) {
            bf16x8 af[4], bfv[NT];
            #pragma unroll
            for (int mt = 0; mt < 4; mt++) {
                int row = wm * 64 + mt * 16 + l16;
                int cb  = (kk >> 3) + quad;
                af[mt] = *(const bf16x8*)(As[cur] + row * 64 + ((cb ^ (row & 7)) * 8));
            }
            #pragma unroll
            for (int nt = 0; nt < NT; nt++) {
                int row = wn * (BN / 2) + nt * 16 + l16;
                int cb  = (kk >> 3) + quad;
                bfv[nt] = *(const bf16x8*)(Bs[cur] + row * 64 + ((cb ^ (row & 7)) * 8));
            }
            #pragma unroll
            for (int mt = 0; mt < 4; mt++)
                #pragma unroll
                for (int nt = 0; nt < NT; nt++)
                    acc[mt][nt] = __builtin_amdgcn_mfma_f32_16x16x32_bf16(
                        af[mt], bfv[nt], acc[mt][nt], 0, 0, 0);
        }
        if (it + 1 < len) store_tiles(cur ^ 1);
        cur ^= 1;
    }

    if (splitN > 1) {
        float* pout = partial + (size_t)sp * pstride;
        #pragma unroll
        for (int mt = 0; mt < 4; mt++)
            #pragma unroll
            for (int nt = 0; nt < NT; nt++)
                #pragma unroll
                for (int r = 0; r < 4; r++) {
                    int mg = m0 + wm * 64 + mt * 16 + quad * 4 + r;
                    int ng = n0 + wn * (BN / 2) + nt * 16 + l16;
                    pout[(size_t)mg * Cout + ng] = acc[mt][nt][r];
                }
    } else {
        #pragma unroll
        for (int mt = 0; mt < 4; mt++)
            #pragma unroll
            for (int nt = 0; nt < NT; nt++)
                #pragma unroll
                for (int r = 0; r < 4; r++) {
                    int mg = m0 + wm * 64 + mt * 16 + quad * 4 + r;
                    int ng = n0 + wn * (BN / 2) + nt * 16 + l16;
                    float v = acc[mt][nt][r] + bias[ng];
                    v = fmaxf(v, 0.f);
                    out[(size_t)mg * Cout + ng] = f2bf(v);
                }
    }
}

// sum split partials + bias + relu -> bf16 NHWC
__global__ void reduce_split(const float* __restrict__ partial,
                             const float* __restrict__ bias, u16* __restrict__ out,
                             int MN, int N, int splitN, size_t pstride)
{
    int i4 = (blockIdx.x * 256 + threadIdx.x) * 4;
    if (i4 >= MN) return;
    float4 s = *(const float4*)(partial + i4);
    for (int sp = 1; sp < splitN; sp++) {
        float4 p = *(const float4*)(partial + (size_t)sp * pstride + i4);
        s.x += p.x; s.y += p.y; s.z += p.z; s.w += p.w;
    }
    int n = i4 & (N - 1);
    ushort4 o;
    o.x = f2bf(fmaxf(s.x + bias[n + 0], 0.f));
    o.y = f2bf(fmaxf(s.y + bias[n + 1], 0.f));
    o.z = f2bf(fmaxf(s.z + bias[n + 2], 0.f));
    o.w = f2bf(fmaxf(s.w + bias[n + 3], 0.f));
    *(ushort4*)(out + i4) = o;
}

// ---------------------------------------------------------------------------
// Generic small GEMM: out[M,N] = act(A[M,K](bf16) @ Bt[N,K](bf16)^T + bias)
// ---------------------------------------------------------------------------
template <bool RELU, bool OUTBF>
__global__ __launch_bounds__(256) void gemm64(
    const u16* __restrict__ A, const u16* __restrict__ Bt,
    const float* __restrict__ bias, void* __restrict__ outv,
    int M, int N, int K)
{
    constexpr int LDP = 72;
    __shared__ u16 As[64 * LDP];
    __shared__ u16 Bs[64 * LDP];

    const int nb = N >> 6;
    const int m0 = (blockIdx.x / nb) * 64;
    const int n0 = (blockIdx.x % nb) * 64;
    const int t = threadIdx.x, lane = t & 63, wave = t >> 6;
    const int quad = lane >> 4, l16 = lane & 15;
    const int wm = wave >> 1, wn = wave & 1;
    const int col8 = t & 7, r0 = t >> 3;

    floatx4 acc[2][2];
    #pragma unroll
    for (int i = 0; i < 2; i++)
        #pragma unroll
        for (int j = 0; j < 2; j++)
            acc[i][j] = (floatx4){0.f, 0.f, 0.f, 0.f};

    for (int kb = 0; kb < K; kb += 64) {
        #pragma unroll
        for (int j = 0; j < 2; j++) {
            int row = r0 + 32 * j;
            *(uint4*)(As + row * LDP + col8 * 8) =
                *(const uint4*)(A + (size_t)(m0 + row) * K + kb + col8 * 8);
            *(uint4*)(Bs + row * LDP + col8 * 8) =
                *(const uint4*)(Bt + (size_t)(n0 + row) * K + kb + col8 * 8);
        }
        __syncthreads();
        #pragma unroll
        for (int kk = 0; kk < 64; kk += 32) {
            bf16x8 af[2], bfv[2];
            #pragma unroll
            for (int mt = 0; mt < 2; mt++)
                af[mt] = *(const bf16x8*)(As + (wm * 32 + mt * 16 + l16) * LDP + kk + quad * 8);
            #pragma unroll
            for (int nt = 0; nt < 2; nt++)
                bfv[nt] = *(const bf16x8*)(Bs + (wn * 32 + nt * 16 + l16) * LDP + kk + quad * 8);
            #pragma unroll
            for (int mt = 0; mt < 2; mt++)
                #pragma unroll
                for (int nt = 0; nt < 2; nt++)
                    acc[mt][nt] = __builtin_amdgcn_mfma_f32_16x16x32_bf16(
                        af[mt], bfv[nt], acc[mt][nt], 0, 0, 0);
        }
        __syncthreads();
    }
    #pragma unroll
    for (int mt = 0; mt < 2; mt++) {
        #pragma unroll
        for (int nt = 0; nt < 2; nt++) {
            #pragma unroll
            for (int r = 0; r < 4; r++) {
                int mg = m0 + wm * 32 + mt * 16 + quad * 4 + r;
                int ng = n0 + wn * 32 + nt * 16 + l16;
                float v = acc[mt][nt][r] + bias[ng];
                if (RELU) v = fmaxf(v, 0.f);
                if (OUTBF) ((u16*)outv)[(size_t)mg * N + ng] = f2bf(v);
                else       ((float*)outv)[(size_t)mg * N + ng] = v;
            }
        }
    }
}

// ---------------------------------------------------------------------------
__global__ __launch_bounds__(256) void graph_tile(
    const float* __restrict__ low, const int* __restrict__ target,
    float* __restrict__ gpre, float* __restrict__ ggt)
{
    __shared__ float Al[64 * 132];
    __shared__ float Bl[128 * 68];
    const int t = threadIdx.x;
    const int gr0 = (blockIdx.x >> 3) * 64;
    const int gc0 = (blockIdx.x & 7) * 64;

    #pragma unroll
    for (int j = 0; j < 32; j++) {
        int flat = t + 256 * j;
        int k = flat & 127;
        int rc = flat >> 7;
        Al[rc * 132 + k] = low[(size_t)(gr0 + rc) * 128 + k];
        Bl[k * 68 + rc]  = low[(size_t)(gc0 + rc) * 128 + k];
    }
    __syncthreads();

    const int tx = t & 15, ty = t >> 4;
    float acc[4][4];
    #pragma unroll
    for (int r = 0; r < 4; r++)
        #pragma unroll
        for (int c = 0; c < 4; c++) acc[r][c] = 0.f;

    for (int k = 0; k < 128; k++) {
        float a[4], b[4];
        #pragma unroll
        for (int r = 0; r < 4; r++) a[r] = Al[(ty * 4 + r) * 132 + k];
        #pragma unroll
        for (int c = 0; c < 4; c++) b[c] = Bl[k * 68 + tx * 4 + c];
        #pragma unroll
        for (int r = 0; r < 4; r++)
            #pragma unroll
            for (int c = 0; c < 4; c++) acc[r][c] += a[r] * b[c];
    }
    #pragma unroll
    for (int r = 0; r < 4; r++) {
        int row = gr0 + ty * 4 + r;
        int tr  = target[row];
        float4 gp, gg;
        float* pp = (float*)&gp;
        float* gg_ = (float*)&gg;
        #pragma unroll
        for (int c = 0; c < 4; c++) {
            pp[c]  = 1.f / (1.f + __expf(-acc[r][c]));
            gg_[c] = (tr == target[gc0 + tx * 4 + c]) ? 1.f : 0.f;
        }
        *(float4*)(gpre + (size_t)row * 512 + gc0 + tx * 4) = gp;
        *(float4*)(ggt  + (size_t)row * 512 + gc0 + tx * 4) = gg;
    }
}

// ---------------------------------------------------------------------------
__global__ __launch_bounds__(256) void cls_kernel(
    const u16* __restrict__ feat, const float* __restrict__ w,
    const float* __restrict__ bias, float* __restrict__ out)
{
    __shared__ float ws[5120];
    const int t = threadIdx.x;
    for (int i = t; i < 5120; i += 256) ws[i] = w[i];
    __syncthreads();
    const int lane = t & 63;
    const int row  = blockIdx.x * 4 + (t >> 6);
    float a[10];
    #pragma unroll
    for (int j = 0; j < 10; j++) a[j] = 0.f;
    #pragma unroll
    for (int i = 0; i < 8; i++) {
        int k = i * 64 + lane;
        float f = bf2f(feat[(size_t)row * 512 + k]);
        #pragma unroll
        for (int j = 0; j < 10; j++) a[j] += f * ws[k * 10 + j];
    }
    #pragma unroll
    for (int j = 0; j < 10; j++)
        #pragma unroll
        for (int off = 32; off > 0; off >>= 1)
            a[j] += __shfl_down(a[j], off, 64);
    if (lane == 0) {
        #pragma unroll
        for (int j = 0; j < 10; j++) out[row * 10 + j] = a[j] + bias[j];
    }
}

// ---------------------------------------------------------------------------
__global__ void pool2(const u16* __restrict__ in, u16* __restrict__ out,
                      int Hout, int C, int total)
{
    int i = blockIdx.x * 256 + threadIdx.x;
    if (i >= total) return;
    int c = i % C;
    int rest = i / C;
    int x = rest % Hout; rest /= Hout;
    int y = rest % Hout;
    int b = rest / Hout;
    int Hin = Hout * 2;
    const u16* p = in + ((size_t)((b * Hin + 2 * y) * Hin + 2 * x) * C + c);
    float v0 = bf2f(p[0]);
    float v1 = bf2f(p[C]);
    float v2 = bf2f(p[(size_t)Hin * C]);
    float v3 = bf2f(p[(size_t)Hin * C + C]);
    out[i] = f2bf(fmaxf(fmaxf(v0, v1), fmaxf(v2, v3)));
}

// ---------------------------------------------------------------------------
extern "C" void kernel_launch(void* const* d_in, const int* in_sizes, int n_in,
                              void* d_out, int out_size, void* d_ws, size_t ws_size,
                              hipStream_t stream)
{
    const float* x      = (const float*)d_in[0];
    const int*   target = (const int*)d_in[1];
    const float* conv_w[13];
    const float* conv_b[13];
    for (int i = 0; i < 13; i++) {
        conv_w[i] = (const float*)d_in[2 + 2 * i];
        conv_b[i] = (const float*)d_in[3 + 2 * i];
    }
    const float* lin1_w = (const float*)d_in[28];
    const float* lin1_b = (const float*)d_in[29];
    const float* lin2_w = (const float*)d_in[30];
    const float* lin2_b = (const float*)d_in[31];
    const float* cls_w  = (const float*)d_in[32];
    const float* cls_b  = (const float*)d_in[33];
    float* out = (float*)d_out;

    static const int cin_arr[13]  = {3, 64, 64, 128, 128, 256, 256, 256, 512, 512, 512, 512, 512};
    static const int cout_arr[13] = {64, 64, 128, 128, 256, 256, 256, 512, 512, 512, 512, 512, 512};

    char* ws = (char*)d_ws;
    size_t off = 0;
    char* R0raw = ws + off; off += (size_t)512 * 32 * 32 * 64 * 2;
    char* R1raw = ws + off; off += (size_t)512 * 32 * 32 * 64 * 2;
    u16* R0 = (u16*)R0raw;
    u16* R1 = (u16*)R1raw;
    float* P0 = (float*)(R0raw + 33554432);   // split-K partials alias upper half
    float* P1 = (float*)(R1raw + 33554432);
    u16* wt[13];
    for (int i = 1; i < 13; i++) {
        wt[i] = (u16*)(ws + off);
        off += (size_t)cout_arr[i] * 9 * cin_arr[i] * 2;
    }
    u16* wtl1 = (u16*)(ws + off); off += (size_t)256 * 512 * 2;
    u16* wtl2 = (u16*)(ws + off); off += (size_t)128 * 256 * 2;
    u16* hbuf = (u16*)(ws + off); off += (size_t)512 * 256 * 2;
    float* lowbuf = (float*)(ws + off); off += (size_t)512 * 128 * 4;

    for (int i = 1; i < 13; i++) {
        int total = cout_arr[i] * 9 * cin_arr[i];
        repack_w<<<(total + 255) / 256, 256, 0, stream>>>(conv_w[i], wt[i], cin_arr[i], total);
    }
    repack_lin<<<(512 * 256) / 256, 256, 0, stream>>>(lin1_w, wtl1, 512, 256, 512 * 256);
    repack_lin<<<(256 * 128) / 256, 256, 0, stream>>>(lin2_w, wtl2, 256, 128, 256 * 128);

    conv0_kernel<<<512 * 8, 256, 0, stream>>>(x, conv_w[0], conv_b[0], R0);

    auto launch_conv = [&](int li, int Hl, u16* inb, u16* outb, float* part, int splitN) {
        int Cin = cin_arr[li], Cout = cout_arr[li];
        int M = 512 * Hl * Hl;
        int logW = __builtin_ctz(Hl);
        int logHW = 2 * logW;
        size_t pstride = (size_t)M * Cout;
        if (Cout >= 128) {
            int grid = (M / 128) * (Cout / 128) * splitN;
            conv_gemm<128><<<grid, 256, 0, stream>>>(
                inb, wt[li], conv_b[li], outb, part, pstride,
                Hl, Cin, Cout, logHW, logW, splitN);
        } else {
            int grid = (M / 128) * (Cout / 64) * splitN;
            conv_gemm<64><<<grid, 256, 0, stream>>>(
                inb, wt[li], conv_b[li], outb, part, pstride,
                Hl, Cin, Cout, logHW, logW, splitN);
        }
        if (splitN > 1) {
            int MN = M * Cout;
            reduce_split<<<(MN / 4 + 255) / 256, 256, 0, stream>>>(
                part, conv_b[li], outb, MN, Cout, splitN, pstride);
        }
    };
    auto launch_pool = [&](int Hout, int C, u16* inb, u16* outb) {
        int total = 512 * Hout * Hout * C;
        pool2<<<(total + 255) / 256, 256, 0, stream>>>(inb, outb, Hout, C, total);
    };

    launch_conv(1, 32, R0, R1, nullptr, 1);
    launch_pool(16, 64, R1, R0);
    launch_conv(2, 16, R0, R1, nullptr, 1);
    launch_conv(3, 16, R1, R0, nullptr, 1);
    launch_pool(8, 128, R0, R1);
    launch_conv(4, 8, R1, R0, nullptr, 1);
    launch_conv(5, 8, R0, R1, nullptr, 1);
    launch_conv(6, 8, R1, R0, nullptr, 1);
    launch_pool(4, 256, R0, R1);
    launch_conv(7, 4, R1, R0, P0, 2);     // T=36 -> 18 iters, 512 blocks
    launch_conv(8, 4, R0, R1, P1, 2);     // T=72 -> 36 iters, 512 blocks
    launch_conv(9, 4, R1, R0, P0, 2);
    launch_pool(2, 512, R0, R1);
    launch_conv(10, 2, R1, R0, P0, 8);    // T=72 -> 9 iters, 512 blocks
    launch_conv(11, 2, R0, R1, P1, 8);
    launch_conv(12, 2, R1, R0, P0, 8);
    launch_pool(1, 512, R0, R1);          // feat bf16 [512,512] in R1

    gemm64<true, true><<<(512 / 64) * (256 / 64), 256, 0, stream>>>(
        R1, wtl1, lin1_b, hbuf, 512, 256, 512);
    gemm64<false, false><<<(512 / 64) * (128 / 64), 256, 0, stream>>>(
        hbuf, wtl2, lin2_b, lowbuf, 512, 128, 256);
    graph_tile<<<64, 256, 0, stream>>>(lowbuf, target, out + 5120, out + 5120 + 262144);
    cls_kernel<<<128, 256, 0, stream>>>(R1, cls_w, cls_b, out);
}